// Round 19
// baseline (162.337 us; speedup 1.0000x reference)
//
#include <hip/hip_runtime.h>
#include <hip/hip_bf16.h>

#define B_   2
#define N_   2048
#define D_   1024
#define H_   16
#define HD   64
#define HALF 32
#define M_   (B_*N_)     // 4096
#define DQKV (3*D_)      // 3072

typedef __bf16 bf16x8 __attribute__((ext_vector_type(8)));
typedef float  f32x4  __attribute__((ext_vector_type(4)));
typedef float  f32x16 __attribute__((ext_vector_type(16)));

// ---------------------------------------------------------------- swizzled LDS tile helpers
__device__ __forceinline__ bf16x8 ldfrag(const char* tile, int row, int ch) {
    return *(const bf16x8*)(tile + row * 128 + (((ch) ^ (row & 7)) << 4));
}
__device__ __forceinline__ void stfrag16(char* tile, int row, int ch, uint4 v) {
    *(uint4*)(tile + row * 128 + (((ch) ^ (row & 7)) << 4)) = v;
}

// async global->LDS DMA, 16B per lane; LDS dest = wave-uniform base + lane*16
__device__ __forceinline__ void gld16(const void* g, void* l) {
    __builtin_amdgcn_global_load_lds(
        (const __attribute__((address_space(1))) unsigned int*)g,
        (__attribute__((address_space(3))) unsigned int*)l, 16, 0, 0);
}

__device__ __forceinline__ unsigned pack2(float a, float b) {
    union { __hip_bfloat16 h; unsigned short s; } x, y;
    x.h = __float2bfloat16(a); y.h = __float2bfloat16(b);
    return (unsigned)x.s | ((unsigned)y.s << 16);
}

// frag-major layout for K-side / V operands (per bh slice of N_*HD elems):
//   flat = (((kt*2 + kb)*8 + c)*32 + l31)*8 + e
#define FRAG_OFF(kt, kb, c, l31, e) \
    ((((size_t)((kt) * 2 + (kb)) * 8 + (c)) * 32 + (l31)) * 8 + (e))

// ---------------------------------------------------------------- K_cvt_x + fused rope table
__global__ __launch_bounds__(256) void k_cvt_x(const float* __restrict__ x,
                                               __hip_bfloat16* __restrict__ xb,
                                               float2* __restrict__ cs2) {
    int i = blockIdx.x * 256 + threadIdx.x;          // over elems/4
    float4 v = ((const float4*)x)[i];
    union { ushort4 u; __hip_bfloat16 h[4]; } o;
    o.h[0] = __float2bfloat16(v.x); o.h[1] = __float2bfloat16(v.y);
    o.h[2] = __float2bfloat16(v.z); o.h[3] = __float2bfloat16(v.w);
    ((ushort4*)xb)[i] = o.u;
    if (blockIdx.x < 256) {
        int ti = blockIdx.x * 256 + threadIdx.x;     // 0..65535 = N_*HALF
        int n = ti / HALF, j = ti % HALF;
        float theta = powf(10000.f, -(float)j / (float)HALF);
        float ang = (float)n * theta;
        cs2[ti] = make_float2(cosf(ang), sinf(ang));
    }
}

// transpose+convert: w (1024 x ncols, fp32) -> wt (ncols x 1024, bf16)
__global__ __launch_bounds__(256) void k_cvt_t(const float* __restrict__ w,
                                               __hip_bfloat16* __restrict__ wt, int ncols) {
    __shared__ float tile[32][33];
    int n0 = blockIdx.x * 32, k0 = blockIdx.y * 32;
    int tx = threadIdx.x & 31, ty = threadIdx.x >> 5;   // ty 0..7
#pragma unroll
    for (int i = 0; i < 32; i += 8)
        tile[ty + i][tx] = w[(size_t)(k0 + ty + i) * ncols + n0 + tx];
    __syncthreads();
#pragma unroll
    for (int i = 0; i < 32; i += 8)
        wt[(size_t)(n0 + ty + i) * 1024 + k0 + tx] = __float2bfloat16(tile[tx][ty + i]);
}

// ---------------------------------------------------------------- K1: QKV GEMM (MFMA) + elu+1 + rope
// (R18 version — FROZEN)
__global__ __launch_bounds__(256) void k_qkv(
        const __hip_bfloat16* __restrict__ xb, const __hip_bfloat16* __restrict__ wqT,
        const float* __restrict__ bias, const float2* __restrict__ cs2,
        __hip_bfloat16* __restrict__ qf, __hip_bfloat16* __restrict__ gke,
        __hip_bfloat16* __restrict__ rq, __hip_bfloat16* __restrict__ gk,
        __hip_bfloat16* __restrict__ gv) {
    __shared__ __align__(16) char sAB[2][192 * 128];   // [buf][A 128 rows | B 64 rows]

    const int t    = threadIdx.x;
    const int m0   = blockIdx.y * 128;
    const int n0w  = blockIdx.x * 64;
    const int lane = t & 63;
    const int lrow = lane & 15;
    const int lgrp = lane >> 4;
    const int wid  = t >> 6;
    const int wr   = wid >> 1;          // wave row 0..1 (64 m each)
    const int wc   = wid & 1;           // wave col 0..1 (32 n each)
    const int lr8  = lane >> 3;         // 0..7
    const int cg   = (lane & 7) ^ lr8;  // inverse-swizzled source chunk

    auto stage = [&](int buf, int kt) {
        const int k0 = kt * 64;
        char* sA = sAB[buf];
        char* sB = sAB[buf] + 128 * 128;
#pragma unroll
        for (int it = 0; it < 4; ++it) {
            int sb  = (wid * 4 + it) * 64;
            int row = (sb >> 3) + lr8;
            gld16(xb + (size_t)(m0 + row) * D_ + k0 + cg * 8, sA + sb * 16);
        }
#pragma unroll
        for (int it = 0; it < 2; ++it) {
            int sb  = (wid * 2 + it) * 64;
            int row = (sb >> 3) + lr8;
            gld16(wqT + (size_t)(n0w + row) * D_ + k0 + cg * 8, sB + sb * 16);
        }
    };

    f32x4 acc[4][2] = {};

    stage(0, 0);

    for (int kt = 0; kt < D_ / 64; ++kt) {
        const int cur = kt & 1;
        if (kt + 1 < D_ / 64) {
            stage(cur ^ 1, kt + 1);
            asm volatile("s_waitcnt vmcnt(6)" ::: "memory");
        } else {
            asm volatile("s_waitcnt vmcnt(0)" ::: "memory");
        }
        __builtin_amdgcn_s_barrier();

        const char* sA = sAB[cur];
        const char* sB = sAB[cur] + 128 * 128;

        bf16x8 bfr[2][2];
#pragma unroll
        for (int fn = 0; fn < 2; ++fn) {
            bfr[fn][0] = ldfrag(sB, wc * 32 + fn * 16 + lrow, lgrp);
            bfr[fn][1] = ldfrag(sB, wc * 32 + fn * 16 + lrow, 4 + lgrp);
        }
#pragma unroll
        for (int fm = 0; fm < 4; ++fm) {
            bf16x8 a0 = ldfrag(sA, wr * 64 + fm * 16 + lrow, lgrp);
            bf16x8 a1 = ldfrag(sA, wr * 64 + fm * 16 + lrow, 4 + lgrp);
#pragma unroll
            for (int fn = 0; fn < 2; ++fn) {
                acc[fm][fn] = __builtin_amdgcn_mfma_f32_16x16x32_bf16(a0, bfr[fn][0], acc[fm][fn], 0, 0, 0);
                acc[fm][fn] = __builtin_amdgcn_mfma_f32_16x16x32_bf16(a1, bfr[fn][1], acc[fm][fn], 0, 0, 0);
            }
        }

        asm volatile("s_waitcnt lgkmcnt(0)" ::: "memory");
        __builtin_amdgcn_sched_barrier(0);
        __builtin_amdgcn_s_barrier();
    }

#pragma unroll
    for (int fn = 0; fn < 2; ++fn) {
        int c   = n0w + wc * 32 + fn * 16 + lrow;
        int sec = c >> 10;
        int cc  = c & 1023;
        int h   = cc >> 6, dd = cc & 63;
        float bia = bias[c];
#pragma unroll
        for (int fm = 0; fm < 4; ++fm) {
            int mb = m0 + wr * 64 + fm * 16 + lgrp * 4;
            int b  = mb >> 11;
            int n  = mb & (N_ - 1);
            size_t hbase = (size_t)(b * H_ + h) * (N_ * HD);
            if (sec == 2) {
                union { ushort4 u; __hip_bfloat16 hh[4]; } pk;
#pragma unroll
                for (int r = 0; r < 4; ++r)
                    pk.hh[r] = __float2bfloat16(acc[fm][fn][r] + bia);
                size_t fo = FRAG_OFF(n >> 6, dd >> 5, (n & 63) >> 3, dd & 31, n & 7);
                *(ushort4*)(gv + hbase + fo) = pk.u;
            } else {
                int pj = dd >> 1;
                size_t qo0 = hbase + (size_t)n * HD + dd;
                size_t fo0 = hbase + FRAG_OFF(n >> 6, (n >> 5) & 1, dd >> 3,
                                              n & 31, dd & 7);
#pragma unroll
                for (int r = 0; r < 4; ++r) {
                    float val = acc[fm][fn][r] + bia;
                    float e  = val > 0.f ? val + 1.f : __expf(val);   // elu(x)+1
                    float ep = __shfl_xor(e, 1);
                    if ((lane & 1) == 0) {
                        float2 cst = cs2[(n + r) * HALF + pj];
                        float rv0 = e * cst.x - ep * cst.y;
                        float rv1 = e * cst.y + ep * cst.x;
                        unsigned ue = pack2(e, ep);
                        unsigned ur = pack2(rv0, rv1);
                        if (sec == 0) {
                            *(unsigned*)(qf + qo0 + (size_t)r * HD) = ue;
                            *(unsigned*)(rq + qo0 + (size_t)r * HD) = ur;
                        } else {
                            *(unsigned*)(gke + fo0 + 8 * r) = ue;
                            *(unsigned*)(gk  + fo0 + 8 * r) = ur;
                        }
                    }
                }
            }
        }
    }
}

// ---------------------------------------------------------------- K2: fused linear attention
// R19: co-residency round. QBLK=128, 512 thr = 2 q-waves (64 q, unchanged) x
// 4 k-splits (8 rounds each, kt=4r+ks). Grid 512 = 2 blocks/CU at natural
// VGPR=128 -> 4 waves/SIMD (NO forced cap — R9/R12 mechanism absent).
// Inner loop byte-identical to R14/R18. Reduction: 4-way, two db-passes, 48KB.
__global__ __launch_bounds__(512, 2) void k_attn(
        const __hip_bfloat16* __restrict__ qf, const __hip_bfloat16* __restrict__ gke,
        const __hip_bfloat16* __restrict__ rq, const __hip_bfloat16* __restrict__ gk,
        const __hip_bfloat16* __restrict__ gv, __hip_bfloat16* __restrict__ ctxb) {
    __shared__ float sred[12288];      // 48 KB: [ks-1][qw][qb][i][lane] per db-pass

    const int t    = threadIdx.x;
    const int lane = t & 63;
    const int l31  = lane & 31;
    const int h    = lane >> 5;
    const int wid  = t >> 6;        // 0..7
    const int qw   = wid & 1;       // q-wave 0/1
    const int ks   = wid >> 1;      // k-split 0..3

    const int bid = blockIdx.x;
    const int swz = (bid & 7) * 64 + (bid >> 3);
    const int bh  = swz >> 4;           // 0..31
    const int q0  = (swz & 15) * 128;   // q-block base (QBLK=128)
    const size_t base = (size_t)bh * (N_ * HD);
    const int q0w = q0 + qw * 64;       // this wave's 64 q-cols

    // ---- hoist Q-side B-frags (loop-invariant, row-major)
    bf16x8 bq[2][4], bqe[2][4];
#pragma unroll
    for (int qb = 0; qb < 2; ++qb)
#pragma unroll
        for (int kc = 0; kc < 4; ++kc) {
            int row = q0w + qb * 32 + l31;
            int col = kc * 16 + h * 8;
            bq [qb][kc] = *(const bf16x8*)(rq + base + (size_t)row * HD + col);
            bqe[qb][kc] = *(const bf16x8*)(qf + base + (size_t)row * HD + col);
        }

    const __hip_bfloat16* K  = gk  + base;
    const __hip_bfloat16* Ke = gke + base;
    const __hip_bfloat16* V  = gv  + base;

    f32x16 o[2][2] = {};

    for (int r = 0; r < 8; ++r) {
        const int kt = 4 * r + ks;      // this ksplit's 64-k tile

        // ---- QK^T (swapped) + in-register W transform
        bf16x8 wa[2][4];
#pragma unroll
        for (int kb = 0; kb < 2; ++kb) {
            bf16x8 ark[4], ake[4];
#pragma unroll
            for (int kc = 0; kc < 4; ++kc) {
                size_t fo = FRAG_OFF(kt, kb, kc * 2 + h, l31, 0);
                ark[kc] = *(const bf16x8*)(K  + fo);
                ake[kc] = *(const bf16x8*)(Ke + fo);
            }
#pragma unroll
            for (int qb = 0; qb < 2; ++qb) {
                f32x16 num = {}, den = {};
                __builtin_amdgcn_s_setprio(1);
#pragma unroll
                for (int kc = 0; kc < 4; ++kc)
                    num = __builtin_amdgcn_mfma_f32_32x32x16_bf16(ark[kc], bq[qb][kc], num, 0, 0, 0);
#pragma unroll
                for (int kc = 0; kc < 4; ++kc)
                    den = __builtin_amdgcn_mfma_f32_32x32x16_bf16(ake[kc], bqe[qb][kc], den, 0, 0, 0);
                __builtin_amdgcn_s_setprio(0);
                unsigned u0 = pack2(num[0]  * __builtin_amdgcn_rcpf(den[0]),
                                    num[1]  * __builtin_amdgcn_rcpf(den[1]));
                unsigned u1 = pack2(num[2]  * __builtin_amdgcn_rcpf(den[2]),
                                    num[3]  * __builtin_amdgcn_rcpf(den[3]));
                unsigned u2 = pack2(num[4]  * __builtin_amdgcn_rcpf(den[4]),
                                    num[5]  * __builtin_amdgcn_rcpf(den[5]));
                unsigned u3 = pack2(num[6]  * __builtin_amdgcn_rcpf(den[6]),
                                    num[7]  * __builtin_amdgcn_rcpf(den[7]));
                unsigned u4 = pack2(num[8]  * __builtin_amdgcn_rcpf(den[8]),
                                    num[9]  * __builtin_amdgcn_rcpf(den[9]));
                unsigned u5 = pack2(num[10] * __builtin_amdgcn_rcpf(den[10]),
                                    num[11] * __builtin_amdgcn_rcpf(den[11]));
                unsigned u6 = pack2(num[12] * __builtin_amdgcn_rcpf(den[12]),
                                    num[13] * __builtin_amdgcn_rcpf(den[13]));
                unsigned u7 = pack2(num[14] * __builtin_amdgcn_rcpf(den[14]),
                                    num[15] * __builtin_amdgcn_rcpf(den[15]));
                asm volatile("v_permlane32_swap_b32 %0, %1" : "+v"(u0), "+v"(u2));
                asm volatile("v_permlane32_swap_b32 %0, %1" : "+v"(u1), "+v"(u3));
                asm volatile("v_permlane32_swap_b32 %0, %1" : "+v"(u4), "+v"(u6));
                asm volatile("v_permlane32_swap_b32 %0, %1" : "+v"(u5), "+v"(u7));
                union { unsigned uu[4]; bf16x8 v; } f0, f1;
                f0.uu[0] = u0; f0.uu[1] = u1; f0.uu[2] = u2; f0.uu[3] = u3;
                f1.uu[0] = u4; f1.uu[1] = u5; f1.uu[2] = u6; f1.uu[3] = u7;
                wa[qb][kb * 2 + 0] = f0.v;
                wa[qb][kb * 2 + 1] = f1.v;
            }
        }

        // ---- PV: O[q][dv] += W @ V  (frag-major V, db in the kb slot)
#pragma unroll
        for (int db = 0; db < 2; ++db) {
            bf16x8 bv[4];
#pragma unroll
            for (int kc = 0; kc < 4; ++kc)
                bv[kc] = *(const bf16x8*)(V + FRAG_OFF(kt, db, kc * 2 + h, l31, 0));
            __builtin_amdgcn_s_setprio(1);
#pragma unroll
            for (int qb = 0; qb < 2; ++qb)
#pragma unroll
                for (int kc = 0; kc < 4; ++kc)
                    o[qb][db] = __builtin_amdgcn_mfma_f32_32x32x16_bf16(wa[qb][kc], bv[kc], o[qb][db], 0, 0, 0);
            __builtin_amdgcn_s_setprio(0);
        }
    }

    // ---- 4-way k-split reduction, two db-passes (48KB) + epilogue
#pragma unroll
    for (int db = 0; db < 2; ++db) {
        if (ks > 0) {
#pragma unroll
            for (int qb = 0; qb < 2; ++qb)
#pragma unroll
                for (int i = 0; i < 16; ++i)
                    sred[((((ks - 1) * 2 + qw) * 2 + qb) * 16 + i) * 64 + lane] = o[qb][db][i];
        }
        __syncthreads();
        if (ks == 0) {
#pragma unroll
            for (int qb = 0; qb < 2; ++qb)
#pragma unroll
                for (int i = 0; i < 16; ++i) {
                    float v = o[qb][db][i];
#pragma unroll
                    for (int s = 0; s < 3; ++s)
                        v += sred[(((s * 2 + qw) * 2 + qb) * 16 + i) * 64 + lane];
                    int qq = q0w + qb * 32 + (i & 3) + 8 * (i >> 2) + 4 * h;
                    ctxb[base + (size_t)qq * HD + db * 32 + l31] = __float2bfloat16(v);
                }
        }
        __syncthreads();
    }
}

// ---------------------------------------------------------------- K3: out projection (MFMA)
// (R15 BM=64 x BN=128 version — FROZEN)
__global__ __launch_bounds__(256) void k_proj(
        const __hip_bfloat16* __restrict__ ctxb, const __hip_bfloat16* __restrict__ woT,
        const float* __restrict__ bias, float* __restrict__ out) {
    __shared__ __align__(16) char sA[64 * 128];    // 64 rows x 64 bf16 (8KB)
    __shared__ __align__(16) char sB[128 * 128];   // 128 rows (16KB)

    const int t    = threadIdx.x;
    const int m0   = blockIdx.y * 64;
    const int n0w  = blockIdx.x * 128;
    const int lane = t & 63;
    const int lrow = lane & 15;
    const int lgrp = lane >> 4;
    const int wid  = t >> 6;
    const int wr   = wid >> 1;          // wave row 0..1 (32 rows each)
    const int wc   = wid & 1;           // wave col 0..1 (64 cols each)
    const int lr8  = lane >> 3;
    const int cg   = (lane & 7) ^ lr8;

    f32x4 acc[2][4] = {};

    for (int kt = 0; kt < D_ / 64; ++kt) {
        const int k0 = kt * 64;
        const int hh = kt;
        __syncthreads();
#pragma unroll
        for (int it = 0; it < 2; ++it) {
            int sb  = (wid * 2 + it) * 64;
            int row = (sb >> 3) + lr8;           // 0..63
            int m = m0 + row;
            int b = m >> 11, n = m & (N_ - 1);
            gld16(ctxb + ((size_t)(b * H_ + hh) * N_ + n) * HD + cg * 8, sA + sb * 16);
        }
#pragma unroll
        for (int it = 0; it < 4; ++it) {
            int sb  = (wid * 4 + it) * 64;
            int row = (sb >> 3) + lr8;           // 0..127
            gld16(woT + (size_t)(n0w + row) * D_ + k0 + cg * 8, sB + sb * 16);
        }
        __syncthreads();

        bf16x8 bfr[4][2];
#pragma unroll
        for (int fn = 0; fn < 4; ++fn) {
            bfr[fn][0] = ldfrag(sB, wc * 64 + fn * 16 + lrow, lgrp);
            bfr[fn][1] = ldfrag(sB, wc * 64 + fn * 16 + lrow, 4 + lgrp);
        }
#pragma unroll
        for (int fm = 0; fm < 2; ++fm) {
            bf16x8 a0 = ldfrag(sA, wr * 32 + fm * 16 + lrow, lgrp);
            bf16x8 a1 = ldfrag(sA, wr * 32 + fm * 16 + lrow, 4 + lgrp);
#pragma unroll
            for (int fn = 0; fn < 4; ++fn) {
                acc[fm][fn] = __builtin_amdgcn_mfma_f32_16x16x32_bf16(a0, bfr[fn][0], acc[fm][fn], 0, 0, 0);
                acc[fm][fn] = __builtin_amdgcn_mfma_f32_16x16x32_bf16(a1, bfr[fn][1], acc[fm][fn], 0, 0, 0);
            }
        }
    }

#pragma unroll
    for (int fn = 0; fn < 4; ++fn) {
        int c = n0w + wc * 64 + fn * 16 + lrow;
        float bia = bias[c];
#pragma unroll
        for (int fm = 0; fm < 2; ++fm) {
            int m = m0 + wr * 32 + fm * 16 + lgrp * 4;
#pragma unroll
            for (int r = 0; r < 4; ++r)
                out[(size_t)(m + r) * D_ + c] = acc[fm][fn][r] + bia;
        }
    }
}

// ---------------------------------------------------------------- launch
extern "C" void kernel_launch(void* const* d_in, const int* in_sizes, int n_in,
                              void* d_out, int out_size, void* d_ws, size_t ws_size,
                              hipStream_t stream) {
    const float* x     = (const float*)d_in[0];
    const float* w_qkv = (const float*)d_in[1];
    const float* b_qkv = (const float*)d_in[2];
    const float* w_out = (const float*)d_in[3];
    const float* b_out = (const float*)d_in[4];
    float* out = (float*)d_out;

    char* ws = (char*)d_ws;
    const size_t TAB  = (size_t)N_ * HALF * sizeof(float);      // 256 KB each
    const size_t HARR = (size_t)B_ * H_ * N_ * HD * 2;          // 8 MB bf16 each
    float2* cs2 = (float2*)ws;                                  // 512 KB (2 TAB slots)
    char* p = ws + 2 * TAB;
    __hip_bfloat16* qf  = (__hip_bfloat16*)(p);            p += HARR;
    __hip_bfloat16* gke = (__hip_bfloat16*)(p);            p += HARR;   // frag-major
    __hip_bfloat16* rq  = (__hip_bfloat16*)(p);            p += HARR;
    __hip_bfloat16* gk  = (__hip_bfloat16*)(p);            p += HARR;   // frag-major
    __hip_bfloat16* gv  = (__hip_bfloat16*)(p);            p += HARR;   // frag-major
    __hip_bfloat16* xb  = (__hip_bfloat16*)(p);            p += HARR;   // M_*D_ bf16 (8MB)
    __hip_bfloat16* ctxb = xb;      // ctx aliases xb (xb dead after k_qkv)
    __hip_bfloat16* wqT = (__hip_bfloat16*)(p);            p += (size_t)DQKV * D_ * 2;  // 6MB
    __hip_bfloat16* woT = (__hip_bfloat16*)(p);            p += (size_t)D_ * D_ * 2;    // 2MB

    hipLaunchKernelGGL(k_cvt_x, dim3(M_ * D_ / 4 / 256), dim3(256), 0, stream,
                       x, xb, cs2);
    hipLaunchKernelGGL(k_cvt_t, dim3(DQKV / 32, D_ / 32), dim3(256), 0, stream,
                       w_qkv, wqT, DQKV);
    hipLaunchKernelGGL(k_cvt_t, dim3(D_ / 32, D_ / 32), dim3(256), 0, stream,
                       w_out, woT, D_);
    hipLaunchKernelGGL(k_qkv, dim3(DQKV / 64, M_ / 128), dim3(256), 0, stream,
                       xb, wqT, b_qkv, cs2, qf, gke, rq, gk, gv);
    hipLaunchKernelGGL(k_attn, dim3(512), dim3(512), 0, stream,
                       qf, gke, rq, gk, gv, ctxb);
    hipLaunchKernelGGL(k_proj, dim3(D_ / 128, M_ / 64), dim3(256), 0, stream,
                       ctxb, woT, b_out, out);
}

// Round 20
// 155.595 us; speedup vs baseline: 1.0433x; 1.0433x over previous
//
#include <hip/hip_runtime.h>
#include <hip/hip_bf16.h>

#define B_   2
#define N_   2048
#define D_   1024
#define H_   16
#define HD   64
#define HALF 32
#define M_   (B_*N_)     // 4096
#define DQKV (3*D_)      // 3072

typedef __bf16 bf16x8 __attribute__((ext_vector_type(8)));
typedef float  f32x4  __attribute__((ext_vector_type(4)));
typedef float  f32x16 __attribute__((ext_vector_type(16)));

// ---------------------------------------------------------------- swizzled LDS tile helpers
__device__ __forceinline__ bf16x8 ldfrag(const char* tile, int row, int ch) {
    return *(const bf16x8*)(tile + row * 128 + (((ch) ^ (row & 7)) << 4));
}
__device__ __forceinline__ void stfrag16(char* tile, int row, int ch, uint4 v) {
    *(uint4*)(tile + row * 128 + (((ch) ^ (row & 7)) << 4)) = v;
}

// async global->LDS DMA, 16B per lane; LDS dest = wave-uniform base + lane*16
__device__ __forceinline__ void gld16(const void* g, void* l) {
    __builtin_amdgcn_global_load_lds(
        (const __attribute__((address_space(1))) unsigned int*)g,
        (__attribute__((address_space(3))) unsigned int*)l, 16, 0, 0);
}

__device__ __forceinline__ unsigned pack2(float a, float b) {
    union { __hip_bfloat16 h; unsigned short s; } x, y;
    x.h = __float2bfloat16(a); y.h = __float2bfloat16(b);
    return (unsigned)x.s | ((unsigned)y.s << 16);
}

// frag-major layout for K-side / V operands (per bh slice of N_*HD elems):
//   flat = (((kt*2 + kb)*8 + c)*32 + l31)*8 + e
#define FRAG_OFF(kt, kb, c, l31, e) \
    ((((size_t)((kt) * 2 + (kb)) * 8 + (c)) * 32 + (l31)) * 8 + (e))

// ---------------------------------------------------------------- K_cvt_x + fused rope table
__global__ __launch_bounds__(256) void k_cvt_x(const float* __restrict__ x,
                                               __hip_bfloat16* __restrict__ xb,
                                               float2* __restrict__ cs2) {
    int i = blockIdx.x * 256 + threadIdx.x;          // over elems/4
    float4 v = ((const float4*)x)[i];
    union { ushort4 u; __hip_bfloat16 h[4]; } o;
    o.h[0] = __float2bfloat16(v.x); o.h[1] = __float2bfloat16(v.y);
    o.h[2] = __float2bfloat16(v.z); o.h[3] = __float2bfloat16(v.w);
    ((ushort4*)xb)[i] = o.u;
    if (blockIdx.x < 256) {
        int ti = blockIdx.x * 256 + threadIdx.x;     // 0..65535 = N_*HALF
        int n = ti / HALF, j = ti % HALF;
        float theta = powf(10000.f, -(float)j / (float)HALF);
        float ang = (float)n * theta;
        cs2[ti] = make_float2(cosf(ang), sinf(ang));
    }
}

// transpose+convert: w (1024 x ncols, fp32) -> wt (ncols x 1024, bf16)
__global__ __launch_bounds__(256) void k_cvt_t(const float* __restrict__ w,
                                               __hip_bfloat16* __restrict__ wt, int ncols) {
    __shared__ float tile[32][33];
    int n0 = blockIdx.x * 32, k0 = blockIdx.y * 32;
    int tx = threadIdx.x & 31, ty = threadIdx.x >> 5;   // ty 0..7
#pragma unroll
    for (int i = 0; i < 32; i += 8)
        tile[ty + i][tx] = w[(size_t)(k0 + ty + i) * ncols + n0 + tx];
    __syncthreads();
#pragma unroll
    for (int i = 0; i < 32; i += 8)
        wt[(size_t)(n0 + ty + i) * 1024 + k0 + tx] = __float2bfloat16(tile[tx][ty + i]);
}

// ---------------------------------------------------------------- K1: QKV GEMM (MFMA) + elu+1 + rope
// (R18 version — FROZEN)
__global__ __launch_bounds__(256) void k_qkv(
        const __hip_bfloat16* __restrict__ xb, const __hip_bfloat16* __restrict__ wqT,
        const float* __restrict__ bias, const float2* __restrict__ cs2,
        __hip_bfloat16* __restrict__ qf, __hip_bfloat16* __restrict__ gke,
        __hip_bfloat16* __restrict__ rq, __hip_bfloat16* __restrict__ gk,
        __hip_bfloat16* __restrict__ gv) {
    __shared__ __align__(16) char sAB[2][192 * 128];   // [buf][A 128 rows | B 64 rows]

    const int t    = threadIdx.x;
    const int m0   = blockIdx.y * 128;
    const int n0w  = blockIdx.x * 64;
    const int lane = t & 63;
    const int lrow = lane & 15;
    const int lgrp = lane >> 4;
    const int wid  = t >> 6;
    const int wr   = wid >> 1;          // wave row 0..1 (64 m each)
    const int wc   = wid & 1;           // wave col 0..1 (32 n each)
    const int lr8  = lane >> 3;         // 0..7
    const int cg   = (lane & 7) ^ lr8;  // inverse-swizzled source chunk

    auto stage = [&](int buf, int kt) {
        const int k0 = kt * 64;
        char* sA = sAB[buf];
        char* sB = sAB[buf] + 128 * 128;
#pragma unroll
        for (int it = 0; it < 4; ++it) {
            int sb  = (wid * 4 + it) * 64;
            int row = (sb >> 3) + lr8;
            gld16(xb + (size_t)(m0 + row) * D_ + k0 + cg * 8, sA + sb * 16);
        }
#pragma unroll
        for (int it = 0; it < 2; ++it) {
            int sb  = (wid * 2 + it) * 64;
            int row = (sb >> 3) + lr8;
            gld16(wqT + (size_t)(n0w + row) * D_ + k0 + cg * 8, sB + sb * 16);
        }
    };

    f32x4 acc[4][2] = {};

    stage(0, 0);

    for (int kt = 0; kt < D_ / 64; ++kt) {
        const int cur = kt & 1;
        if (kt + 1 < D_ / 64) {
            stage(cur ^ 1, kt + 1);
            asm volatile("s_waitcnt vmcnt(6)" ::: "memory");
        } else {
            asm volatile("s_waitcnt vmcnt(0)" ::: "memory");
        }
        __builtin_amdgcn_s_barrier();

        const char* sA = sAB[cur];
        const char* sB = sAB[cur] + 128 * 128;

        bf16x8 bfr[2][2];
#pragma unroll
        for (int fn = 0; fn < 2; ++fn) {
            bfr[fn][0] = ldfrag(sB, wc * 32 + fn * 16 + lrow, lgrp);
            bfr[fn][1] = ldfrag(sB, wc * 32 + fn * 16 + lrow, 4 + lgrp);
        }
#pragma unroll
        for (int fm = 0; fm < 4; ++fm) {
            bf16x8 a0 = ldfrag(sA, wr * 64 + fm * 16 + lrow, lgrp);
            bf16x8 a1 = ldfrag(sA, wr * 64 + fm * 16 + lrow, 4 + lgrp);
#pragma unroll
            for (int fn = 0; fn < 2; ++fn) {
                acc[fm][fn] = __builtin_amdgcn_mfma_f32_16x16x32_bf16(a0, bfr[fn][0], acc[fm][fn], 0, 0, 0);
                acc[fm][fn] = __builtin_amdgcn_mfma_f32_16x16x32_bf16(a1, bfr[fn][1], acc[fm][fn], 0, 0, 0);
            }
        }

        asm volatile("s_waitcnt lgkmcnt(0)" ::: "memory");
        __builtin_amdgcn_sched_barrier(0);
        __builtin_amdgcn_s_barrier();
    }

#pragma unroll
    for (int fn = 0; fn < 2; ++fn) {
        int c   = n0w + wc * 32 + fn * 16 + lrow;
        int sec = c >> 10;
        int cc  = c & 1023;
        int h   = cc >> 6, dd = cc & 63;
        float bia = bias[c];
#pragma unroll
        for (int fm = 0; fm < 4; ++fm) {
            int mb = m0 + wr * 64 + fm * 16 + lgrp * 4;
            int b  = mb >> 11;
            int n  = mb & (N_ - 1);
            size_t hbase = (size_t)(b * H_ + h) * (N_ * HD);
            if (sec == 2) {
                union { ushort4 u; __hip_bfloat16 hh[4]; } pk;
#pragma unroll
                for (int r = 0; r < 4; ++r)
                    pk.hh[r] = __float2bfloat16(acc[fm][fn][r] + bia);
                size_t fo = FRAG_OFF(n >> 6, dd >> 5, (n & 63) >> 3, dd & 31, n & 7);
                *(ushort4*)(gv + hbase + fo) = pk.u;
            } else {
                int pj = dd >> 1;
                size_t qo0 = hbase + (size_t)n * HD + dd;
                size_t fo0 = hbase + FRAG_OFF(n >> 6, (n >> 5) & 1, dd >> 3,
                                              n & 31, dd & 7);
#pragma unroll
                for (int r = 0; r < 4; ++r) {
                    float val = acc[fm][fn][r] + bia;
                    float e  = val > 0.f ? val + 1.f : __expf(val);   // elu(x)+1
                    float ep = __shfl_xor(e, 1);
                    if ((lane & 1) == 0) {
                        float2 cst = cs2[(n + r) * HALF + pj];
                        float rv0 = e * cst.x - ep * cst.y;
                        float rv1 = e * cst.y + ep * cst.x;
                        unsigned ue = pack2(e, ep);
                        unsigned ur = pack2(rv0, rv1);
                        if (sec == 0) {
                            *(unsigned*)(qf + qo0 + (size_t)r * HD) = ue;
                            *(unsigned*)(rq + qo0 + (size_t)r * HD) = ur;
                        } else {
                            *(unsigned*)(gke + fo0 + 8 * r) = ue;
                            *(unsigned*)(gk  + fo0 + 8 * r) = ur;
                        }
                    }
                }
            }
        }
    }
}

// ---------------------------------------------------------------- K2: fused linear attention
// R14/R18-EXACT (best-known, restored): barrier-free frag-major, 512 thr =
// 4 q-waves x 2 k-splits, QBLK=256, grid 256, (512,2), T5 setprio.
__global__ __launch_bounds__(512, 2) void k_attn(
        const __hip_bfloat16* __restrict__ qf, const __hip_bfloat16* __restrict__ gke,
        const __hip_bfloat16* __restrict__ rq, const __hip_bfloat16* __restrict__ gk,
        const __hip_bfloat16* __restrict__ gv, __hip_bfloat16* __restrict__ ctxb) {
    __shared__ float sred[16384];      // 64 KB, epilogue reduction only

    const int t    = threadIdx.x;
    const int lane = t & 63;
    const int l31  = lane & 31;
    const int h    = lane >> 5;
    const int wid  = t >> 6;        // 0..7
    const int qw   = wid & 3;       // q-wave
    const int ks   = wid >> 2;      // k-split 0/1

    const int bid = blockIdx.x;
    const int swz = (bid & 7) * 32 + (bid >> 3);
    const int bh  = swz >> 3;           // 0..31
    const int q0  = (swz & 7) * 256;    // q-block base (QBLK=256)
    const size_t base = (size_t)bh * (N_ * HD);
    const int q0w = q0 + qw * 64;       // this wave's 64 q-cols

    // ---- hoist Q-side B-frags (loop-invariant, row-major)
    bf16x8 bq[2][4], bqe[2][4];
#pragma unroll
    for (int qb = 0; qb < 2; ++qb)
#pragma unroll
        for (int kc = 0; kc < 4; ++kc) {
            int row = q0w + qb * 32 + l31;
            int col = kc * 16 + h * 8;
            bq [qb][kc] = *(const bf16x8*)(rq + base + (size_t)row * HD + col);
            bqe[qb][kc] = *(const bf16x8*)(qf + base + (size_t)row * HD + col);
        }

    const __hip_bfloat16* K  = gk  + base;
    const __hip_bfloat16* Ke = gke + base;
    const __hip_bfloat16* V  = gv  + base;

    f32x16 o[2][2] = {};

    for (int r = 0; r < 16; ++r) {
        const int kt = 2 * r + ks;      // this ksplit's 64-k tile

        // ---- QK^T (swapped) + in-register W transform
        bf16x8 wa[2][4];
#pragma unroll
        for (int kb = 0; kb < 2; ++kb) {
            bf16x8 ark[4], ake[4];
#pragma unroll
            for (int kc = 0; kc < 4; ++kc) {
                size_t fo = FRAG_OFF(kt, kb, kc * 2 + h, l31, 0);
                ark[kc] = *(const bf16x8*)(K  + fo);
                ake[kc] = *(const bf16x8*)(Ke + fo);
            }
#pragma unroll
            for (int qb = 0; qb < 2; ++qb) {
                f32x16 num = {}, den = {};
                __builtin_amdgcn_s_setprio(1);
#pragma unroll
                for (int kc = 0; kc < 4; ++kc)
                    num = __builtin_amdgcn_mfma_f32_32x32x16_bf16(ark[kc], bq[qb][kc], num, 0, 0, 0);
#pragma unroll
                for (int kc = 0; kc < 4; ++kc)
                    den = __builtin_amdgcn_mfma_f32_32x32x16_bf16(ake[kc], bqe[qb][kc], den, 0, 0, 0);
                __builtin_amdgcn_s_setprio(0);
                unsigned u0 = pack2(num[0]  * __builtin_amdgcn_rcpf(den[0]),
                                    num[1]  * __builtin_amdgcn_rcpf(den[1]));
                unsigned u1 = pack2(num[2]  * __builtin_amdgcn_rcpf(den[2]),
                                    num[3]  * __builtin_amdgcn_rcpf(den[3]));
                unsigned u2 = pack2(num[4]  * __builtin_amdgcn_rcpf(den[4]),
                                    num[5]  * __builtin_amdgcn_rcpf(den[5]));
                unsigned u3 = pack2(num[6]  * __builtin_amdgcn_rcpf(den[6]),
                                    num[7]  * __builtin_amdgcn_rcpf(den[7]));
                unsigned u4 = pack2(num[8]  * __builtin_amdgcn_rcpf(den[8]),
                                    num[9]  * __builtin_amdgcn_rcpf(den[9]));
                unsigned u5 = pack2(num[10] * __builtin_amdgcn_rcpf(den[10]),
                                    num[11] * __builtin_amdgcn_rcpf(den[11]));
                unsigned u6 = pack2(num[12] * __builtin_amdgcn_rcpf(den[12]),
                                    num[13] * __builtin_amdgcn_rcpf(den[13]));
                unsigned u7 = pack2(num[14] * __builtin_amdgcn_rcpf(den[14]),
                                    num[15] * __builtin_amdgcn_rcpf(den[15]));
                asm volatile("v_permlane32_swap_b32 %0, %1" : "+v"(u0), "+v"(u2));
                asm volatile("v_permlane32_swap_b32 %0, %1" : "+v"(u1), "+v"(u3));
                asm volatile("v_permlane32_swap_b32 %0, %1" : "+v"(u4), "+v"(u6));
                asm volatile("v_permlane32_swap_b32 %0, %1" : "+v"(u5), "+v"(u7));
                union { unsigned uu[4]; bf16x8 v; } f0, f1;
                f0.uu[0] = u0; f0.uu[1] = u1; f0.uu[2] = u2; f0.uu[3] = u3;
                f1.uu[0] = u4; f1.uu[1] = u5; f1.uu[2] = u6; f1.uu[3] = u7;
                wa[qb][kb * 2 + 0] = f0.v;
                wa[qb][kb * 2 + 1] = f1.v;
            }
        }

        // ---- PV: O[q][dv] += W @ V  (frag-major V, db in the kb slot)
#pragma unroll
        for (int db = 0; db < 2; ++db) {
            bf16x8 bv[4];
#pragma unroll
            for (int kc = 0; kc < 4; ++kc)
                bv[kc] = *(const bf16x8*)(V + FRAG_OFF(kt, db, kc * 2 + h, l31, 0));
            __builtin_amdgcn_s_setprio(1);
#pragma unroll
            for (int qb = 0; qb < 2; ++qb)
#pragma unroll
                for (int kc = 0; kc < 4; ++kc)
                    o[qb][db] = __builtin_amdgcn_mfma_f32_32x32x16_bf16(wa[qb][kc], bv[kc], o[qb][db], 0, 0, 0);
            __builtin_amdgcn_s_setprio(0);
        }
    }

    // ---- k-split reduction (LDS) + epilogue
    if (ks == 1) {
#pragma unroll
        for (int qb = 0; qb < 2; ++qb)
#pragma unroll
            for (int db = 0; db < 2; ++db)
#pragma unroll
                for (int i = 0; i < 16; ++i)
                    sred[(((qw * 2 + qb) * 2 + db) << 10) + i * 64 + lane] = o[qb][db][i];
    }
    __syncthreads();
    if (ks == 0) {
#pragma unroll
        for (int qb = 0; qb < 2; ++qb)
#pragma unroll
            for (int db = 0; db < 2; ++db)
#pragma unroll
                for (int i = 0; i < 16; ++i) {
                    float v = o[qb][db][i] + sred[(((qw * 2 + qb) * 2 + db) << 10) + i * 64 + lane];
                    int qq = q0w + qb * 32 + (i & 3) + 8 * (i >> 2) + 4 * h;
                    ctxb[base + (size_t)qq * HD + db * 32 + l31] = __float2bfloat16(v);
                }
    }
}

// ---------------------------------------------------------------- K3: out projection (MFMA)
// (R15 BM=64 x BN=128 version — FROZEN)
__global__ __launch_bounds__(256) void k_proj(
        const __hip_bfloat16* __restrict__ ctxb, const __hip_bfloat16* __restrict__ woT,
        const float* __restrict__ bias, float* __restrict__ out) {
    __shared__ __align__(16) char sA[64 * 128];    // 64 rows x 64 bf16 (8KB)
    __shared__ __align__(16) char sB[128 * 128];   // 128 rows (16KB)

    const int t    = threadIdx.x;
    const int m0   = blockIdx.y * 64;
    const int n0w  = blockIdx.x * 128;
    const int lane = t & 63;
    const int lrow = lane & 15;
    const int lgrp = lane >> 4;
    const int wid  = t >> 6;
    const int wr   = wid >> 1;          // wave row 0..1 (32 rows each)
    const int wc   = wid & 1;           // wave col 0..1 (64 cols each)
    const int lr8  = lane >> 3;
    const int cg   = (lane & 7) ^ lr8;

    f32x4 acc[2][4] = {};

    for (int kt = 0; kt < D_ / 64; ++kt) {
        const int k0 = kt * 64;
        const int hh = kt;
        __syncthreads();
#pragma unroll
        for (int it = 0; it < 2; ++it) {
            int sb  = (wid * 2 + it) * 64;
            int row = (sb >> 3) + lr8;           // 0..63
            int m = m0 + row;
            int b = m >> 11, n = m & (N_ - 1);
            gld16(ctxb + ((size_t)(b * H_ + hh) * N_ + n) * HD + cg * 8, sA + sb * 16);
        }
#pragma unroll
        for (int it = 0; it < 4; ++it) {
            int sb  = (wid * 4 + it) * 64;
            int row = (sb >> 3) + lr8;           // 0..127
            gld16(woT + (size_t)(n0w + row) * D_ + k0 + cg * 8, sB + sb * 16);
        }
        __syncthreads();

        bf16x8 bfr[4][2];
#pragma unroll
        for (int fn = 0; fn < 4; ++fn) {
            bfr[fn][0] = ldfrag(sB, wc * 64 + fn * 16 + lrow, lgrp);
            bfr[fn][1] = ldfrag(sB, wc * 64 + fn * 16 + lrow, 4 + lgrp);
        }
#pragma unroll
        for (int fm = 0; fm < 2; ++fm) {
            bf16x8 a0 = ldfrag(sA, wr * 32 + fm * 16 + lrow, lgrp);
            bf16x8 a1 = ldfrag(sA, wr * 32 + fm * 16 + lrow, 4 + lgrp);
#pragma unroll
            for (int fn = 0; fn < 4; ++fn) {
                acc[fm][fn] = __builtin_amdgcn_mfma_f32_16x16x32_bf16(a0, bfr[fn][0], acc[fm][fn], 0, 0, 0);
                acc[fm][fn] = __builtin_amdgcn_mfma_f32_16x16x32_bf16(a1, bfr[fn][1], acc[fm][fn], 0, 0, 0);
            }
        }
    }

#pragma unroll
    for (int fn = 0; fn < 4; ++fn) {
        int c = n0w + wc * 64 + fn * 16 + lrow;
        float bia = bias[c];
#pragma unroll
        for (int fm = 0; fm < 2; ++fm) {
            int m = m0 + wr * 32 + fm * 16 + lgrp * 4;
#pragma unroll
            for (int r = 0; r < 4; ++r)
                out[(size_t)(m + r) * D_ + c] = acc[fm][fn][r] + bia;
        }
    }
}

// ---------------------------------------------------------------- launch
extern "C" void kernel_launch(void* const* d_in, const int* in_sizes, int n_in,
                              void* d_out, int out_size, void* d_ws, size_t ws_size,
                              hipStream_t stream) {
    const float* x     = (const float*)d_in[0];
    const float* w_qkv = (const float*)d_in[1];
    const float* b_qkv = (const float*)d_in[2];
    const float* w_out = (const float*)d_in[3];
    const float* b_out = (const float*)d_in[4];
    float* out = (float*)d_out;

    char* ws = (char*)d_ws;
    const size_t TAB  = (size_t)N_ * HALF * sizeof(float);      // 256 KB each
    const size_t HARR = (size_t)B_ * H_ * N_ * HD * 2;          // 8 MB bf16 each
    float2* cs2 = (float2*)ws;                                  // 512 KB (2 TAB slots)
    char* p = ws + 2 * TAB;
    __hip_bfloat16* qf  = (__hip_bfloat16*)(p);            p += HARR;
    __hip_bfloat16* gke = (__hip_bfloat16*)(p);            p += HARR;   // frag-major
    __hip_bfloat16* rq  = (__hip_bfloat16*)(p);            p += HARR;
    __hip_bfloat16* gk  = (__hip_bfloat16*)(p);            p += HARR;   // frag-major
    __hip_bfloat16* gv  = (__hip_bfloat16*)(p);            p += HARR;   // frag-major
    __hip_bfloat16* xb  = (__hip_bfloat16*)(p);            p += HARR;   // M_*D_ bf16 (8MB)
    __hip_bfloat16* ctxb = xb;      // ctx aliases xb (xb dead after k_qkv)
    __hip_bfloat16* wqT = (__hip_bfloat16*)(p);            p += (size_t)DQKV * D_ * 2;  // 6MB
    __hip_bfloat16* woT = (__hip_bfloat16*)(p);            p += (size_t)D_ * D_ * 2;    // 2MB

    hipLaunchKernelGGL(k_cvt_x, dim3(M_ * D_ / 4 / 256), dim3(256), 0, stream,
                       x, xb, cs2);
    hipLaunchKernelGGL(k_cvt_t, dim3(DQKV / 32, D_ / 32), dim3(256), 0, stream,
                       w_qkv, wqT, DQKV);
    hipLaunchKernelGGL(k_cvt_t, dim3(D_ / 32, D_ / 32), dim3(256), 0, stream,
                       w_out, woT, D_);
    hipLaunchKernelGGL(k_qkv, dim3(DQKV / 64, M_ / 128), dim3(256), 0, stream,
                       xb, wqT, b_qkv, cs2, qf, gke, rq, gk, gv);
    hipLaunchKernelGGL(k_attn, dim3(256), dim3(512), 0, stream,
                       qf, gke, rq, gk, gv, ctxb);
    hipLaunchKernelGGL(k_proj, dim3(D_ / 128, M_ / 64), dim3(256), 0, stream,
                       ctxb, woT, b_out, out);
}